// Round 6
// baseline (187.264 us; speedup 1.0000x reference)
//
#include <hip/hip_runtime.h>
#include <hip/hip_cooperative_groups.h>
#include <hip/hip_bf16.h>
#include <stdint.h>
#include <math.h>

// ColBERT MaxSim on MI355X (gfx950) — single cooperative fused kernel.
// phase0: W -> WT bf16 swizzled | grid.sync | phase1: proj (64 rows/block,
// BK=128, dbuf LDS, T14 A-prefetch, L2-normalize, 16-slot-swizzled reps) |
// grid.sync | phase2: score (32x32x16 MFMA, D=A/Q=B so doc-max is
// in-register, Q staged once + frags hoisted, D dbuf via global_load_lds,
// maxAll overlay on dead Q-tile, inline mask, direct stores, no atomics).
// 256 blocks x 512 threads, 128 KB LDS -> exactly 1 block/CU (cooperative-safe).

namespace cg = cooperative_groups;

#define BQ 32
#define LQ 256
#define V  768
#define DIM 128
#define NQ (BQ * LQ)       // 8192 query tokens
#define ND (BQ * LQ)       // 8192 doc tokens

typedef short bf16x8 __attribute__((ext_vector_type(8)));
typedef float f32x4  __attribute__((ext_vector_type(4)));
typedef float f32x16 __attribute__((ext_vector_type(16)));
typedef float fvec4  __attribute__((ext_vector_type(4)));
typedef unsigned short us4 __attribute__((ext_vector_type(4)));

__device__ inline unsigned short f2bf(float f) {
  __hip_bfloat16 h = __float2bfloat16(f);
  unsigned short u;
  __builtin_memcpy(&u, &h, 2);
  return u;
}

__device__ inline void gload_lds16(const void* g, void* lds) {
  __builtin_amdgcn_global_load_lds(
      (const __attribute__((address_space(1))) void*)g,
      (__attribute__((address_space(3))) void*)lds, 16, 0, 0);
}

__launch_bounds__(512, 2)
__global__ void colbert_fused(const float* __restrict__ qh,
                              const float* __restrict__ dh,
                              const float* __restrict__ W,
                              const float* __restrict__ bias,
                              const int* __restrict__ mask,
                              unsigned short* __restrict__ WT,
                              unsigned short* __restrict__ qrep,
                              unsigned short* __restrict__ drep,
                              float* __restrict__ out) {
  __shared__ __align__(16) char smem[131072];
  const int t = threadIdx.x;
  const int blk = blockIdx.x;
  const int w = t >> 6, l = t & 63;

  // ============ phase 0: W [768][128] f32 -> WT bf16 [n][k] swizzled ======
  // WT row n (0..127), stride 1536 B; per-64k group (128 B): 16B chunk c at
  // c ^ (n&7), within-chunk pos (k&7)*2.
  {
    int idx = blk * 512 + t;   // 131072 threads cover 98304 elements
    if (idx < 98304) {
      int n = idx & 127, k = idx >> 7;
      float v = W[idx];
      int kg = k >> 6, kc = k & 63;
      int wb = ((((kc >> 3) ^ (n & 7)) << 4) | ((kc & 7) << 1));
      *(unsigned short*)((char*)WT + (size_t)n * 1536 + kg * 128 + wb) = f2bf(v);
    }
  }
  cg::this_grid().sync();

  // ============ phase 1: projection, 64 rows/block, BK=128 (6 steps) ======
  {
    char* At = smem;                       // 2 bufs x (2 halves x 64 rows x 128 B) = 32 KB
    char* Bt = smem + 32768;               // 2 bufs x (2 halves x 128 n x 128 B) = 64 KB
    float* sq = (float*)(smem + 98304);    // [4 wc][64 rows]
    const int lm = l & 15, lg = l >> 4;
    const int wr2 = w >> 2, wc = w & 3;    // 2 (row-dir) x 4 (col-dir) waves
    const int rowblk = blk * 64;

    // A-load assignment: 4 float4 per thread (64 rows x 32 chunks)
    int arow[4], ac4[4];
    const float* asrc[4];
    #pragma unroll
    for (int p = 0; p < 4; p++) {
      int id = p * 512 + t;
      arow[p] = id >> 5;          // 0..63
      ac4[p]  = id & 31;          // float4 chunk within 128 k
      int row_g = rowblk + arow[p];
      asrc[p] = (row_g < NQ) ? (qh + (size_t)row_g * V)
                             : (dh + (size_t)(row_g - NQ) * V);
    }

    f32x4 acc[2][2];
    #pragma unroll
    for (int r = 0; r < 2; r++)
      #pragma unroll
      for (int c = 0; c < 2; c++)
        acc[r][c] = f32x4{0.f, 0.f, 0.f, 0.f};

    float bias_c[2];
    #pragma unroll
    for (int c = 0; c < 2; c++) bias_c[c] = bias[wc * 32 + c * 16 + lm];

    fvec4 ap[4];
    // ---- prologue: stage step 0 ----
    #pragma unroll
    for (int p = 0; p < 4; p++) ap[p] = *(const fvec4*)(asrc[p] + ac4[p] * 4);
    #pragma unroll
    for (int i = 0; i < 4; i++) {
      int off = i * 8192 + t * 16;
      int h = off >> 14, offh = off & 16383;
      int n = offh >> 7, inr = offh & 127;
      gload_lds16((const char*)WT + (size_t)n * 1536 + h * 128 + inr, Bt + off);
    }
    #pragma unroll
    for (int p = 0; p < 4; p++) {
      us4 b4;
      #pragma unroll
      for (int j = 0; j < 4; j++) b4[j] = f2bf(ap[p][j]);
      int h = ac4[p] >> 4, kc4 = ac4[p] & 15;
      int wb = ((((kc4 >> 1) ^ (arow[p] & 7)) << 4) | ((kc4 & 1) << 3));
      *(us4*)(At + h * 8192 + arow[p] * 128 + wb) = b4;
    }
    __syncthreads();

    // ---- main loop: 6 K-steps of 128 ----
    for (int kk = 0; kk < 6; kk++) {
      const int cur = kk & 1;
      char* curA = At + cur * 16384;
      char* curB = Bt + (cur << 15);
      if (kk < 5) {
        #pragma unroll
        for (int p = 0; p < 4; p++)
          ap[p] = *(const fvec4*)(asrc[p] + (kk + 1) * 128 + ac4[p] * 4);
        char* nxtB = Bt + ((cur ^ 1) << 15);
        #pragma unroll
        for (int i = 0; i < 4; i++) {
          int off = i * 8192 + t * 16;
          int h = off >> 14, offh = off & 16383;
          int n = offh >> 7, inr = offh & 127;
          gload_lds16((const char*)WT + (size_t)n * 1536 + ((kk + 1) * 2 + h) * 128 + inr,
                      nxtB + off);
        }
      }
      // compute current buffers: 4 k-slices of 32
      #pragma unroll
      for (int ks = 0; ks < 4; ks++) {
        const int h = ks >> 1, ksl = ks & 1;
        bf16x8 af[2], bfr[2];
        #pragma unroll
        for (int r = 0; r < 2; r++) {
          int row = wr2 * 32 + r * 16 + lm;
          int ch = (ksl * 4 + lg) ^ (row & 7);
          af[r] = *(const bf16x8*)(curA + h * 8192 + row * 128 + ch * 16);
        }
        #pragma unroll
        for (int c = 0; c < 2; c++) {
          int n = wc * 32 + c * 16 + lm;
          int ch = (ksl * 4 + lg) ^ (n & 7);
          bfr[c] = *(const bf16x8*)(curB + h * 16384 + n * 128 + ch * 16);
        }
        #pragma unroll
        for (int r = 0; r < 2; r++)
          #pragma unroll
          for (int c = 0; c < 2; c++)
            acc[r][c] = __builtin_amdgcn_mfma_f32_16x16x32_bf16(af[r], bfr[c], acc[r][c], 0, 0, 0);
      }
      if (kk < 5) {
        char* nxtA = At + (cur ^ 1) * 16384;
        #pragma unroll
        for (int p = 0; p < 4; p++) {
          us4 b4;
          #pragma unroll
          for (int j = 0; j < 4; j++) b4[j] = f2bf(ap[p][j]);
          int h = ac4[p] >> 4, kc4 = ac4[p] & 15;
          int wb = ((((kc4 >> 1) ^ (arow[p] & 7)) << 4) | ((kc4 & 1) << 3));
          *(us4*)(nxtA + h * 8192 + arow[p] * 128 + wb) = b4;
        }
      }
      __syncthreads();
    }

    // ---- epilogue: bias, sum-of-squares, normalize, swizzled rep store ----
    float vout[2][2][4];
    float ss[2][4];
    #pragma unroll
    for (int r = 0; r < 2; r++) {
      #pragma unroll
      for (int j = 0; j < 4; j++) {
        float s = 0.f;
        #pragma unroll
        for (int c = 0; c < 2; c++) {
          float v = acc[r][c][j] + bias_c[c];
          vout[r][c][j] = v;
          s += v * v;
        }
        #pragma unroll
        for (int m = 1; m < 16; m <<= 1) s += __shfl_xor(s, m, 64);
        ss[r][j] = s;
      }
    }
    if (lm == 0) {
      #pragma unroll
      for (int r = 0; r < 2; r++)
        #pragma unroll
        for (int j = 0; j < 4; j++)
          sq[wc * 64 + wr2 * 32 + r * 16 + lg * 4 + j] = ss[r][j];
    }
    __syncthreads();
    #pragma unroll
    for (int r = 0; r < 2; r++) {
      #pragma unroll
      for (int j = 0; j < 4; j++) {
        int brow = wr2 * 32 + r * 16 + lg * 4 + j;
        float tot = sq[brow] + sq[64 + brow] + sq[128 + brow] + sq[192 + brow];
        float inv = 1.0f / fmaxf(sqrtf(tot), 1e-12f);
        int row_g = rowblk + brow;
        unsigned short* rep = (row_g < NQ) ? qrep : drep;
        int rl = (row_g < NQ) ? row_g : row_g - NQ;
        #pragma unroll
        for (int c = 0; c < 2; c++) {
          int col = wc * 32 + c * 16 + lm;
          int byteoff = rl * 256 + ((((col >> 3) ^ (rl & 15)) << 4) | ((col & 7) << 1));
          *(unsigned short*)((char*)rep + byteoff) = f2bf(vout[r][c][j] * inv);
        }
      }
    }
  }
  cg::this_grid().sync();

  // ============ phase 2: score — qb = blk>>3, dg = blk&7 ============
  {
    char* Qt  = smem;                        // 64 KB, dead after qf hoist
    char* Dt0 = smem + 65536;                // 32 KB
    char* Dt1 = smem + 98304;                // 32 KB
    float* maxAll   = (float*)smem;          // [4 db][2 wr][256 q] overlay
    float* partial2 = (float*)(smem + 8192); // [8] overlay

    const int col = l & 31, hi = l >> 5;
    const int wr = w >> 2, wc = w & 3;   // 2 (d-dir) x 4 (q-dir)
    const int qb = blk >> 3;
    const int dg = blk & 7;

    const char* qsrc = (const char*)qrep + (size_t)qb * 65536;
    const char* dsrc = (const char*)drep + (size_t)dg * 262144;

    #pragma unroll
    for (int i = 0; i < 8; i++)
      gload_lds16(qsrc + i * 8192 + t * 16, Qt + i * 8192 + w * 1024);
    #pragma unroll
    for (int i = 0; i < 4; i++)
      gload_lds16(dsrc + i * 8192 + t * 16, Dt0 + i * 8192 + w * 1024);
    __syncthreads();

    // hoist Q-frags (2 col-tiles x 8 k-steps); Qt dead afterwards
    bf16x8 qf[2][8];
    #pragma unroll
    for (int c = 0; c < 2; c++) {
      int n = wc * 64 + c * 32 + col;
      const char* rowb = Qt + n * 256;
      #pragma unroll
      for (int ks = 0; ks < 8; ks++) {
        int ch = (ks * 2 + hi) ^ (n & 15);
        qf[c][ks] = *(const bf16x8*)(rowb + ch * 16);
      }
    }

    f32x16 acc[2][2];
    float vmax[2] = {-INFINITY, -INFINITY};

    for (int db = 0; db < 4; db++) {
      // phase A: stage chunk 2db+1 -> Dt1; compute chunk 2db from Dt0
      {
        const char* nsrc = dsrc + (size_t)(2 * db + 1) * 32768;
        #pragma unroll
        for (int i = 0; i < 4; i++)
          gload_lds16(nsrc + i * 8192 + t * 16, Dt1 + i * 8192 + w * 1024);
      }
      #pragma unroll
      for (int r = 0; r < 2; r++)
        #pragma unroll
        for (int c = 0; c < 2; c++)
          #pragma unroll
          for (int g = 0; g < 16; g++) acc[r][c][g] = 0.f;
      #pragma unroll
      for (int ks = 0; ks < 8; ks++) {
        bf16x8 df[2];
        #pragma unroll
        for (int r = 0; r < 2; r++) {
          int m = wr * 64 + r * 32 + col;
          int ch = (ks * 2 + hi) ^ (m & 15);
          df[r] = *(const bf16x8*)(Dt0 + m * 256 + ch * 16);
        }
        #pragma unroll
        for (int r = 0; r < 2; r++)
          #pragma unroll
          for (int c = 0; c < 2; c++)
            acc[r][c] = __builtin_amdgcn_mfma_f32_32x32x16_bf16(df[r], qf[c][ks], acc[r][c], 0, 0, 0);
      }
      #pragma unroll
      for (int c = 0; c < 2; c++)
        #pragma unroll
        for (int r = 0; r < 2; r++)
          #pragma unroll
          for (int g = 0; g < 16; g++) vmax[c] = fmaxf(vmax[c], acc[r][c][g]);
      __syncthreads();  // chunk 2db+1 landed; all waves done with Dt0

      // phase B: stage chunk 2db+2 -> Dt0 (if any); compute Dt1
      if (db < 3) {
        const char* nsrc = dsrc + (size_t)(2 * db + 2) * 32768;
        #pragma unroll
        for (int i = 0; i < 4; i++)
          gload_lds16(nsrc + i * 8192 + t * 16, Dt0 + i * 8192 + w * 1024);
      }
      #pragma unroll
      for (int r = 0; r < 2; r++)
        #pragma unroll
        for (int c = 0; c < 2; c++)
          #pragma unroll
          for (int g = 0; g < 16; g++) acc[r][c][g] = 0.f;
      #pragma unroll
      for (int ks = 0; ks < 8; ks++) {
        bf16x8 df[2];
        #pragma unroll
        for (int r = 0; r < 2; r++) {
          int m = wr * 64 + r * 32 + col;
          int ch = (ks * 2 + hi) ^ (m & 15);
          df[r] = *(const bf16x8*)(Dt1 + m * 256 + ch * 16);
        }
        #pragma unroll
        for (int r = 0; r < 2; r++)
          #pragma unroll
          for (int c = 0; c < 2; c++)
            acc[r][c] = __builtin_amdgcn_mfma_f32_32x32x16_bf16(df[r], qf[c][ks], acc[r][c], 0, 0, 0);
      }
      #pragma unroll
      for (int c = 0; c < 2; c++)
        #pragma unroll
        for (int r = 0; r < 2; r++)
          #pragma unroll
          for (int g = 0; g < 16; g++) vmax[c] = fmaxf(vmax[c], acc[r][c][g]);

      // per-db store: combine hi-halves, write per-token max
      #pragma unroll
      for (int c = 0; c < 2; c++) {
        float m = vmax[c];
        m = fmaxf(m, __shfl_xor(m, 32, 64));
        if (hi == 0) maxAll[db * 512 + wr * 256 + wc * 64 + c * 32 + col] = m;
        vmax[c] = -INFINITY;
      }
      __syncthreads();  // Dt0 DMA landed; Dt1 free; maxAll[db] visible
    }

    // final epilogue: wave w -> db = w>>1, half h = w&1; inline mask
    {
      int s = 0;
      #pragma unroll
      for (int p = 0; p < 4; p++) s += mask[qb * 256 + p * 64 + l];
      #pragma unroll
      for (int off = 1; off < 64; off <<= 1) s += __shfl_xor(s, off, 64);
      int sep = s - 1;
      int db = w >> 1, h = w & 1;
      int tok0 = h * 128 + l;
      int tok1 = tok0 + 64;
      float m0 = fmaxf(maxAll[db * 512 + tok0], maxAll[db * 512 + 256 + tok0]);
      float m1 = fmaxf(maxAll[db * 512 + tok1], maxAll[db * 512 + 256 + tok1]);
      float wm0 = (tok0 != 0 && tok0 != sep) ? (float)mask[qb * 256 + tok0] : 0.f;
      float wm1 = (tok1 != 0 && tok1 != sep) ? (float)mask[qb * 256 + tok1] : 0.f;
      float contrib = m0 * wm0 + m1 * wm1;
      #pragma unroll
      for (int off = 1; off < 64; off <<= 1) contrib += __shfl_xor(contrib, off, 64);
      if (l == 0) partial2[w] = contrib;
    }
    __syncthreads();
    if (t < 4)
      out[qb * 32 + dg * 4 + t] = partial2[2 * t] + partial2[2 * t + 1];
  }
}

// ---------------------------------------------------------------------------
extern "C" void kernel_launch(void* const* d_in, const int* in_sizes, int n_in,
                              void* d_out, int out_size, void* d_ws, size_t ws_size,
                              hipStream_t stream) {
  const float* qh  = (const float*)d_in[0];
  const float* dh  = (const float*)d_in[1];
  const float* W   = (const float*)d_in[2];
  const float* b   = (const float*)d_in[3];
  const int* mask  = (const int*)d_in[4];
  float* out = (float*)d_out;

  char* ws = (char*)d_ws;
  unsigned short* qrep = (unsigned short*)(ws);                 // 2 MB
  unsigned short* drep = (unsigned short*)(ws + (1 << 21));     // 2 MB
  unsigned short* WT   = (unsigned short*)(ws + (1 << 22));     // 192 KB

  void* args[] = {(void*)&qh, (void*)&dh, (void*)&W, (void*)&b, (void*)&mask,
                  (void*)&WT, (void*)&qrep, (void*)&drep, (void*)&out};
  hipLaunchCooperativeKernel((const void*)colbert_fused, dim3(256), dim3(512),
                             args, 0, stream);
}

// Round 7
// 114.824 us; speedup vs baseline: 1.6309x; 1.6309x over previous
//
#include <hip/hip_runtime.h>
#include <hip/hip_bf16.h>
#include <stdint.h>
#include <math.h>

// ColBERT MaxSim on MI355X (gfx950) — 3-kernel pipeline (fused/coop variant
// was 65 us SLOWER: 2x grid.sync ~ 30 us each on 8 XCDs; reverted).
// prep (W^T->bf16 swizzled) | proj (16x16x32 MFMA, dbuf LDS, T14 A-prefetch,
// L2-normalize, 16-slot-swizzled bf16 reps) | score (32x32x16 MFMA, D=A/Q=B
// so doc-max is in-register, Q staged once + frags hoisted, D dbuf via
// global_load_lds, maxAll overlay on dead Q-tile, inline mask, no atomics).
// Measured context: harness overhead ~94 us/iter is fixed; kernels ~24 us.

#define BQ 32
#define LQ 256
#define V  768
#define DIM 128
#define NQ (BQ * LQ)       // 8192 query tokens
#define ND (BQ * LQ)       // 8192 doc tokens

typedef short bf16x8 __attribute__((ext_vector_type(8)));
typedef float f32x4  __attribute__((ext_vector_type(4)));
typedef float f32x16 __attribute__((ext_vector_type(16)));
typedef float fvec4  __attribute__((ext_vector_type(4)));
typedef unsigned short us4 __attribute__((ext_vector_type(4)));

__device__ inline unsigned short f2bf(float f) {
  __hip_bfloat16 h = __float2bfloat16(f);
  unsigned short u;
  __builtin_memcpy(&u, &h, 2);
  return u;
}

__device__ inline void gload_lds16(const void* g, void* lds) {
  __builtin_amdgcn_global_load_lds(
      (const __attribute__((address_space(1))) void*)g,
      (__attribute__((address_space(3))) void*)lds, 16, 0, 0);
}

// ---------------------------------------------------------------------------
// prep: W [768][128] f32 -> WT bf16 [n][k] (128 x 768), 8-slot chunk swizzle
// key (n&7), row stride 1536 B (consumed by proj's LDS path).
__global__ void prep_kernel(const float* __restrict__ W,
                            unsigned short* __restrict__ WT) {
  int idx = blockIdx.x * 256 + threadIdx.x;  // idx = k*128 + n
  int n = idx & 127;
  int k = idx >> 7;
  float v = W[idx];
  int kg = k >> 6;
  int kc = k & 63;
  int wb = ((((kc >> 3) ^ (n & 7)) << 4) | ((kc & 7) << 1));
  *(unsigned short*)((char*)WT + (size_t)n * 1536 + kg * 128 + wb) = f2bf(v);
}

// ---------------------------------------------------------------------------
// proj: rows of [qry;doc] hidden (f32, K=768) @ W + b, L2-normalize, store
// bf16 reps with 16-slot chunk swizzle (key row&15) for score's LDS path.
// Block: 32 rows x 128 cols, 4 waves, wave-tile 32x32. Double-buffered
// A (reg-staged, T14 split) and B (global_load_lds). One barrier per K-step.
__launch_bounds__(256, 2)
__global__ void proj_kernel(const float* __restrict__ qh, const float* __restrict__ dh,
                            const unsigned short* __restrict__ WT,
                            const float* __restrict__ bias,
                            unsigned short* __restrict__ qrep,
                            unsigned short* __restrict__ drep) {
  __shared__ __align__(16) unsigned short At[2][32 * 64];   // 2 x 4 KB swizzled
  __shared__ __align__(16) unsigned short Bt[2][128 * 64];  // 2 x 16 KB swizzled
  __shared__ float sq[4][32];

  const int t = threadIdx.x;
  const int w = t >> 6;
  const int l = t & 63;
  const int lm = l & 15, lg = l >> 4;
  const int rowblk = blockIdx.x * 32;

  // per-thread A-load assignment: 2 float4 chunks (32 rows x 16 chunks)
  int arow[2], ac4[2];
  const float* asrc[2];
  #pragma unroll
  for (int p = 0; p < 2; p++) {
    int id = p * 256 + t;
    arow[p] = id >> 4;
    ac4[p] = id & 15;
    int row_g = rowblk + arow[p];
    asrc[p] = (row_g < NQ) ? (qh + (size_t)row_g * V)
                           : (dh + (size_t)(row_g - NQ) * V);
  }

  f32x4 acc[2][2];
  #pragma unroll
  for (int r = 0; r < 2; r++)
    #pragma unroll
    for (int c = 0; c < 2; c++)
      acc[r][c] = f32x4{0.f, 0.f, 0.f, 0.f};

  float bias_c[2];
  #pragma unroll
  for (int c = 0; c < 2; c++) bias_c[c] = bias[w * 32 + c * 16 + lm];

  fvec4 apref[2];
  // ---- prologue (kk = 0) ----
  #pragma unroll
  for (int p = 0; p < 2; p++) apref[p] = *(const fvec4*)(asrc[p] + ac4[p] * 4);
  #pragma unroll
  for (int i = 0; i < 4; i++) {
    int off = i * 4096 + t * 16;
    int n = off >> 7, inrow = off & 127;
    gload_lds16((const char*)WT + (size_t)n * 1536 + inrow,
                (char*)Bt[0] + i * 4096 + w * 1024);
  }
  #pragma unroll
  for (int p = 0; p < 2; p++) {
    us4 b4;
    #pragma unroll
    for (int j = 0; j < 4; j++) b4[j] = f2bf(apref[p][j]);
    int wb = ((((ac4[p] >> 1) ^ (arow[p] & 7)) << 4) | ((ac4[p] & 1) << 3));
    *(us4*)((char*)At[0] + arow[p] * 128 + wb) = b4;
  }
  __syncthreads();

  // ---- main loop: 12 K-steps of 64 ----
  for (int kk = 0; kk < 12; kk++) {
    const int cur = kk & 1;
    if (kk < 11) {
      // T14: issue next A loads early; DMA next B slice into other buffer
      #pragma unroll
      for (int p = 0; p < 2; p++)
        apref[p] = *(const fvec4*)(asrc[p] + (kk + 1) * 64 + ac4[p] * 4);
      #pragma unroll
      for (int i = 0; i < 4; i++) {
        int off = i * 4096 + t * 16;
        int n = off >> 7, inrow = off & 127;
        gload_lds16((const char*)WT + (size_t)n * 1536 + (kk + 1) * 128 + inrow,
                    (char*)Bt[cur ^ 1] + i * 4096 + w * 1024);
      }
    }
    // compute current buffers
    #pragma unroll
    for (int ks = 0; ks < 2; ks++) {
      bf16x8 af[2], bfr[2];
      #pragma unroll
      for (int r = 0; r < 2; r++) {
        int row = r * 16 + lm;
        int ch = (ks * 4 + lg) ^ (row & 7);
        af[r] = *(const bf16x8*)((char*)At[cur] + row * 128 + ch * 16);
      }
      #pragma unroll
      for (int c = 0; c < 2; c++) {
        int n = w * 32 + c * 16 + lm;
        int ch = (ks * 4 + lg) ^ (n & 7);
        bfr[c] = *(const bf16x8*)((char*)Bt[cur] + n * 128 + ch * 16);
      }
      #pragma unroll
      for (int r = 0; r < 2; r++)
        #pragma unroll
        for (int c = 0; c < 2; c++)
          acc[r][c] = __builtin_amdgcn_mfma_f32_16x16x32_bf16(af[r], bfr[c], acc[r][c], 0, 0, 0);
    }
    if (kk < 11) {
      // late half of T14 split: convert + ds_write into next buffer
      #pragma unroll
      for (int p = 0; p < 2; p++) {
        us4 b4;
        #pragma unroll
        for (int j = 0; j < 4; j++) b4[j] = f2bf(apref[p][j]);
        int wb = ((((ac4[p] >> 1) ^ (arow[p] & 7)) << 4) | ((ac4[p] & 1) << 3));
        *(us4*)((char*)At[cur ^ 1] + arow[p] * 128 + wb) = b4;
      }
    }
    __syncthreads();
  }

  // ---- epilogue: bias, sum-of-squares, normalize, swizzled store ----
  float vout[2][2][4];
  float ss[2][4];
  #pragma unroll
  for (int r = 0; r < 2; r++) {
    #pragma unroll
    for (int j = 0; j < 4; j++) {
      float s = 0.f;
      #pragma unroll
      for (int c = 0; c < 2; c++) {
        float v = acc[r][c][j] + bias_c[c];
        vout[r][c][j] = v;
        s += v * v;
      }
      #pragma unroll
      for (int m = 1; m < 16; m <<= 1) s += __shfl_xor(s, m, 64);
      ss[r][j] = s;
    }
  }
  if (lm == 0) {
    #pragma unroll
    for (int r = 0; r < 2; r++)
      #pragma unroll
      for (int j = 0; j < 4; j++)
        sq[w][r * 16 + lg * 4 + j] = ss[r][j];
  }
  __syncthreads();
  #pragma unroll
  for (int r = 0; r < 2; r++) {
    #pragma unroll
    for (int j = 0; j < 4; j++) {
      int rowl = r * 16 + lg * 4 + j;
      float tot = sq[0][rowl] + sq[1][rowl] + sq[2][rowl] + sq[3][rowl];
      float inv = 1.0f / fmaxf(sqrtf(tot), 1e-12f);
      int row_g = rowblk + rowl;
      unsigned short* rep = (row_g < NQ) ? qrep : drep;
      int rl = (row_g < NQ) ? row_g : row_g - NQ;
      #pragma unroll
      for (int c = 0; c < 2; c++) {
        int col = w * 32 + c * 16 + lm;
        int byteoff = rl * 256 + ((((col >> 3) ^ (rl & 15)) << 4) | ((col & 7) << 1));
        *(unsigned short*)((char*)rep + byteoff) = f2bf(vout[r][c][j] * inv);
      }
    }
  }
}

// ---------------------------------------------------------------------------
// score: block = one query batch (256 q) x 4 doc batches (1024 d).
// Grid 32 x 8 = 256 blocks = 1/CU. 8 waves = 2 (d-dir) x 4 (q-dir);
// wave-tile 64 d x 64 q, mfma_f32_32x32x16_bf16 (A = D rows, B = Q cols).
// Q-tile 64 KB staged once (frags hoisted to regs, then Qt is DEAD and
// overlaid by maxAll/partial); D 128-row chunks double-buffered 2x32 KB.
// Max over doc tokens is over REGISTER indices; per-db result -> maxAll.
// Final epilogue computes [SEP] inline from mask (no wmask pass).
// LDS total = 128 KB exactly.
__launch_bounds__(512, 2)
__global__ void score_kernel(const unsigned short* __restrict__ qrep,
                             const unsigned short* __restrict__ drep,
                             const int* __restrict__ mask,
                             float* __restrict__ out) {
  __shared__ __align__(16) char smem[131072];
  char* Qt  = smem;                       // 64 KB, dead after qf hoist
  char* Dt0 = smem + 65536;               // 32 KB
  char* Dt1 = smem + 98304;               // 32 KB
  float* maxAll   = (float*)smem;         // [4 db][2 wr][256 q] = 8 KB (overlay)
  float* partial2 = (float*)(smem + 8192); // [8] (overlay)

  const int t = threadIdx.x;
  const int w = t >> 6, l = t & 63;
  const int col = l & 31, hi = l >> 5;
  const int wr = w >> 2, wc = w & 3;   // 2 (d-dir) x 4 (q-dir)
  const int qb = blockIdx.x;           // 0..31 query batch
  const int dg = blockIdx.y;           // 0..7  doc-batch group

  const char* qsrc = (const char*)qrep + (size_t)qb * 65536;
  const char* dsrc = (const char*)drep + (size_t)dg * 262144;

  // stage Q (64 KB) + D chunk 0 (32 KB)
  #pragma unroll
  for (int i = 0; i < 8; i++)
    gload_lds16(qsrc + i * 8192 + t * 16, Qt + i * 8192 + w * 1024);
  #pragma unroll
  for (int i = 0; i < 4; i++)
    gload_lds16(dsrc + i * 8192 + t * 16, Dt0 + i * 8192 + w * 1024);
  __syncthreads();

  // hoist Q-frags: 2 col-tiles x 8 k-steps (64 VGPR); Qt dead afterwards
  bf16x8 qf[2][8];
  #pragma unroll
  for (int c = 0; c < 2; c++) {
    int n = wc * 64 + c * 32 + col;
    const char* rowb = Qt + n * 256;
    #pragma unroll
    for (int ks = 0; ks < 8; ks++) {
      int ch = (ks * 2 + hi) ^ (n & 15);
      qf[c][ks] = *(const bf16x8*)(rowb + ch * 16);
    }
  }

  f32x16 acc[2][2];
  float vmax[2] = {-INFINITY, -INFINITY};

  for (int db = 0; db < 4; db++) {
    // ---- phase A: stage chunk 2db+1 -> Dt1; compute chunk 2db from Dt0
    {
      const char* nsrc = dsrc + (size_t)(2 * db + 1) * 32768;
      #pragma unroll
      for (int i = 0; i < 4; i++)
        gload_lds16(nsrc + i * 8192 + t * 16, Dt1 + i * 8192 + w * 1024);
    }
    #pragma unroll
    for (int r = 0; r < 2; r++)
      #pragma unroll
      for (int c = 0; c < 2; c++)
        #pragma unroll
        for (int g = 0; g < 16; g++) acc[r][c][g] = 0.f;
    #pragma unroll
    for (int ks = 0; ks < 8; ks++) {
      bf16x8 df[2];
      #pragma unroll
      for (int r = 0; r < 2; r++) {
        int m = wr * 64 + r * 32 + col;
        int ch = (ks * 2 + hi) ^ (m & 15);
        df[r] = *(const bf16x8*)(Dt0 + m * 256 + ch * 16);
      }
      #pragma unroll
      for (int r = 0; r < 2; r++)
        #pragma unroll
        for (int c = 0; c < 2; c++)
          acc[r][c] = __builtin_amdgcn_mfma_f32_32x32x16_bf16(df[r], qf[c][ks], acc[r][c], 0, 0, 0);
    }
    #pragma unroll
    for (int c = 0; c < 2; c++)
      #pragma unroll
      for (int r = 0; r < 2; r++)
        #pragma unroll
        for (int g = 0; g < 16; g++) vmax[c] = fmaxf(vmax[c], acc[r][c][g]);
    __syncthreads();  // chunk 2db+1 landed; all waves done with Dt0

    // ---- phase B: stage chunk 2db+2 -> Dt0 (if any); compute Dt1
    if (db < 3) {
      const char* nsrc = dsrc + (size_t)(2 * db + 2) * 32768;
      #pragma unroll
      for (int i = 0; i < 4; i++)
        gload_lds16(nsrc + i * 8192 + t * 16, Dt0 + i * 8192 + w * 1024);
    }
    #pragma unroll
    for (int r = 0; r < 2; r++)
      #pragma unroll
      for (int c = 0; c < 2; c++)
        #pragma unroll
        for (int g = 0; g < 16; g++) acc[r][c][g] = 0.f;
    #pragma unroll
    for (int ks = 0; ks < 8; ks++) {
      bf16x8 df[2];
      #pragma unroll
      for (int r = 0; r < 2; r++) {
        int m = wr * 64 + r * 32 + col;
        int ch = (ks * 2 + hi) ^ (m & 15);
        df[r] = *(const bf16x8*)(Dt1 + m * 256 + ch * 16);
      }
      #pragma unroll
      for (int r = 0; r < 2; r++)
        #pragma unroll
        for (int c = 0; c < 2; c++)
          acc[r][c] = __builtin_amdgcn_mfma_f32_32x32x16_bf16(df[r], qf[c][ks], acc[r][c], 0, 0, 0);
    }
    #pragma unroll
    for (int c = 0; c < 2; c++)
      #pragma unroll
      for (int r = 0; r < 2; r++)
        #pragma unroll
        for (int g = 0; g < 16; g++) vmax[c] = fmaxf(vmax[c], acc[r][c][g]);

    // ---- per-db store: combine hi-halves, write per-token max (no barrier)
    #pragma unroll
    for (int c = 0; c < 2; c++) {
      float m = vmax[c];
      m = fmaxf(m, __shfl_xor(m, 32, 64));
      if (hi == 0) maxAll[db * 512 + wr * 256 + wc * 64 + c * 32 + col] = m;
      vmax[c] = -INFINITY;
    }
    __syncthreads();  // Dt0 DMA landed; Dt1 free; maxAll[db] visible
  }

  // ---- final epilogue: wave w -> db = w>>1, half h = w&1; inline mask
  {
    int s = 0;
    #pragma unroll
    for (int p = 0; p < 4; p++) s += mask[qb * 256 + p * 64 + l];
    #pragma unroll
    for (int off = 1; off < 64; off <<= 1) s += __shfl_xor(s, off, 64);
    int sep = s - 1;
    int db = w >> 1, h = w & 1;
    int tok0 = h * 128 + l;
    int tok1 = tok0 + 64;
    float m0 = fmaxf(maxAll[db * 512 + tok0], maxAll[db * 512 + 256 + tok0]);
    float m1 = fmaxf(maxAll[db * 512 + tok1], maxAll[db * 512 + 256 + tok1]);
    float wm0 = (tok0 != 0 && tok0 != sep) ? (float)mask[qb * 256 + tok0] : 0.f;
    float wm1 = (tok1 != 0 && tok1 != sep) ? (float)mask[qb * 256 + tok1] : 0.f;
    float contrib = m0 * wm0 + m1 * wm1;
    #pragma unroll
    for (int off = 1; off < 64; off <<= 1) contrib += __shfl_xor(contrib, off, 64);
    if (l == 0) partial2[w] = contrib;
  }
  __syncthreads();
  if (t < 4)
    out[qb * 32 + dg * 4 + t] = partial2[2 * t] + partial2[2 * t + 1];
}

// ---------------------------------------------------------------------------
extern "C" void kernel_launch(void* const* d_in, const int* in_sizes, int n_in,
                              void* d_out, int out_size, void* d_ws, size_t ws_size,
                              hipStream_t stream) {
  const float* qh  = (const float*)d_in[0];
  const float* dh  = (const float*)d_in[1];
  const float* W   = (const float*)d_in[2];
  const float* b   = (const float*)d_in[3];
  const int* mask  = (const int*)d_in[4];
  float* out = (float*)d_out;

  char* ws = (char*)d_ws;
  unsigned short* qrep = (unsigned short*)(ws);                 // 2 MB
  unsigned short* drep = (unsigned short*)(ws + (1 << 21));     // 2 MB
  unsigned short* WT   = (unsigned short*)(ws + (1 << 22));     // 192 KB

  prep_kernel<<<384, 256, 0, stream>>>(W, WT);
  proj_kernel<<<512, 256, 0, stream>>>(qh, dh, WT, b, qrep, drep);
  score_kernel<<<dim3(32, 8), 512, 0, stream>>>(qrep, drep, mask, out);
}